// Round 2
// baseline (393.223 us; speedup 1.0000x reference)
//
#include <hip/hip_runtime.h>

// NonLocalAttention: channel attention restructured around Gram matrix.
//   G = x x^T (per batch, bf16 split precision, split-k partials + tree reduce)
//   logits = Aq G Ak^T + (Aq r) bk^T + bq (Ak r)^T + S*bq bk^T,  Aq = Dq Wq etc.
//   attn = softmax(logits, dim=-1)  (fp32)
//   M = attn Dv Wv (bf16), c = attn bv
//   out = M x + c 1^T + x   (bf16 MFMA, fp32 residual)
//
// R4: resubmission of R3 (bench infra failed twice; no kernel verdict).
// R3 change: kGram was phase-serialized (HBM stage ~6.2K cyc/kt between
// barriers, then LDS-read-bound MFMA phase: 72 b128/wave/kt vs 192 MFMA ->
// MfmaUtil 24%, hbm 20%). Rewritten:
//  (a) 2D wave tiling 4x2 (64x128/wave): B-frags amortized over 4 row-tiles.
//  (b) symmetry trick: G = P + P^T with P = 0.5*hh + hl  (A-side reads hi
//      only, 2 MFMA passes instead of 3; bit-identical precision to bf16x3).
//      Transpose-add applied to the reduced 256x256 G by new tiny kSym.
//  (c) LDS double-buffer + register prefetch: global loads for tile kt+1
//      issue before the MFMA block, convert+write after; 1 barrier/kt.
// LDS reads/kt/wave 72->40, MFMA 192->128, HBM overlapped -> HBM-streaming
// bound (~194 MB, ~31 us floor).

typedef __bf16 bf16x8 __attribute__((ext_vector_type(8)));
typedef float f32x4 __attribute__((ext_vector_type(4)));
typedef unsigned short us8 __attribute__((ext_vector_type(8)));

#define EPS 1e-5f

__device__ __forceinline__ unsigned short f2bf(float f) {
  unsigned int u = __float_as_uint(f);
  u += 0x7fffu + ((u >> 16) & 1u);   // round-to-nearest-even
  return (unsigned short)(u >> 16);
}
__device__ __forceinline__ float bf2f(unsigned short h) {
  return __uint_as_float(((unsigned int)h) << 16);
}
__device__ __forceinline__ bf16x8 ld_frag(const unsigned short* p) {
  union { us8 u; bf16x8 b; } x;
  x.u = *(const us8*)p;
  return x.b;
}

// ---------------------------------------------------------------- kGram ----
// grid (splits, 8 batches), 512 threads (8 waves as 4x2 wave grid).
// Each WG: P = 0.5*Xh Xh^T + Xh (2*Xl)^T partial over a `chunk`-wide S range,
// double-buffered LDS, prefetched global loads. Stores 0.5*acc; kSym later
// forms G = P + P^T.
#define LDB 72   // padded LDS row stride (bf16 elements); 144B, 16B-aligned

#define CONV_WRITE(dst)                                                     \
  _Pragma("unroll")                                                         \
  for (int u = 0; u < 4; ++u) {                                             \
    float fv[8] = {pa[u].x, pa[u].y, pa[u].z, pa[u].w,                      \
                   pb[u].x, pb[u].y, pb[u].z, pb[u].w};                     \
    union { unsigned short s[8]; uint4 v; } H, L;                           \
    _Pragma("unroll")                                                       \
    for (int e = 0; e < 8; ++e) {                                           \
      const unsigned short h = f2bf(fv[e]);                                 \
      H.s[e] = h;                                                           \
      L.s[e] = f2bf(2.0f * (fv[e] - bf2f(h)));                              \
      rs[u] += fv[e];                                                       \
    }                                                                       \
    *(uint4*)&sh[dst][(srow + u * 64) * LDB + sg * 8] = H.v;                \
    *(uint4*)&sl[dst][(srow + u * 64) * LDB + sg * 8] = L.v;                \
  }

__global__ __launch_bounds__(512, 2) void kGram(const float* __restrict__ x,
                                                float* __restrict__ Gp,
                                                float* __restrict__ rp,
                                                int chunk) {
  __shared__ __align__(16) unsigned short sh[2][256 * LDB];  // hi, double-buf
  __shared__ __align__(16) unsigned short sl[2][256 * LDB];  // 2*lo
  const int n = blockIdx.y;
  const int k0 = blockIdx.x * chunk;
  const int nkt = chunk >> 6;
  const int tid = threadIdx.x;
  const float* xn = x + (size_t)n * 4194304;   // 256*16384

  f32x4 acc[4][8];
  const f32x4 z4 = {0.f, 0.f, 0.f, 0.f};
#pragma unroll
  for (int i = 0; i < 4; ++i)
#pragma unroll
    for (int j = 0; j < 8; ++j) acc[i][j] = z4;
  float rs[4] = {0.f, 0.f, 0.f, 0.f};

  const int lane = tid & 63, w = tid >> 6;
  const int m = lane & 15, q = lane >> 4;
  const int wr = w >> 1, wc = w & 1;          // 4x2 wave grid
  const int srow = tid >> 3, sg = tid & 7;    // staging: row, 8-float group

  float4 pa[4], pb[4];

  // prologue: load + convert + write tile 0 into buf 0
#pragma unroll
  for (int u = 0; u < 4; ++u) {
    const float* p = xn + (size_t)(srow + u * 64) * 16384 + k0 + sg * 8;
    pa[u] = *(const float4*)p;
    pb[u] = *(const float4*)(p + 4);
  }
  CONV_WRITE(0)
  __syncthreads();

  for (int kt = 0; kt < nkt; ++kt) {
    const int b = kt & 1;
    const bool more = (kt + 1 < nkt);
    if (more) {   // prefetch next tile into regs; latency hides under MFMAs
      const int kb = k0 + (kt + 1) * 64;
#pragma unroll
      for (int u = 0; u < 4; ++u) {
        const float* p = xn + (size_t)(srow + u * 64) * 16384 + kb + sg * 8;
        pa[u] = *(const float4*)p;
        pb[u] = *(const float4*)(p + 4);
      }
    }
#pragma unroll
    for (int kk = 0; kk < 64; kk += 32) {
      bf16x8 Ah[4];
#pragma unroll
      for (int i = 0; i < 4; ++i)
        Ah[i] = ld_frag(&sh[b][(wr * 64 + i * 16 + m) * LDB + kk + q * 8]);
#pragma unroll
      for (int j = 0; j < 8; ++j) {
        const int off = (wc * 128 + j * 16 + m) * LDB + kk + q * 8;
        const bf16x8 Bh = ld_frag(&sh[b][off]);
        const bf16x8 Bl = ld_frag(&sl[b][off]);
#pragma unroll
        for (int i = 0; i < 4; ++i) {
          acc[i][j] = __builtin_amdgcn_mfma_f32_16x16x32_bf16(Ah[i], Bh, acc[i][j], 0, 0, 0);
          acc[i][j] = __builtin_amdgcn_mfma_f32_16x16x32_bf16(Ah[i], Bl, acc[i][j], 0, 0, 0);
        }
      }
    }
    if (more) {   // convert+write into the other buffer; one barrier per kt
      const int nb = b ^ 1;
      CONV_WRITE(nb)
      __syncthreads();
    }
  }

  const size_t slot = (size_t)n * gridDim.x + blockIdx.x;
  // partial row sums: rows are owned by aligned groups of 8 lanes (bits 0..2)
#pragma unroll
  for (int u = 0; u < 4; ++u) {
    float v = rs[u];
    v += __shfl_xor(v, 1);
    v += __shfl_xor(v, 2);
    v += __shfl_xor(v, 4);
    if ((lane & 7) == 0) rp[slot * 256 + (srow + u * 64)] = v;
  }
  // C/D layout: col = lane&15, row = (lane>>4)*4 + reg
  float* Gpn = Gp + slot * 65536;
#pragma unroll
  for (int i = 0; i < 4; ++i)
#pragma unroll
    for (int j = 0; j < 8; ++j)
#pragma unroll
      for (int e = 0; e < 4; ++e) {
        const int grow = wr * 64 + i * 16 + q * 4 + e;
        const int gcol = wc * 128 + j * 16 + m;
        Gpn[grow * 256 + gcol] = 0.5f * acc[i][j][e];
      }
}

// -------------------------------------------------------------- kReduce ----
// grid 512 x 256: one thread per 4 elements (float4), sums `splits` partials
// IN PLACE into split-0's slot (read-all-then-write, per-thread exclusive).
__global__ void kReduce(float* __restrict__ Gp, int splits) {
  const int e4 = (blockIdx.x * 256 + threadIdx.x) * 4;   // 0 .. 524284
  const int n = e4 >> 16, el = e4 & 65535;
  float* p = Gp + (size_t)n * splits * 65536 + el;
  float4 s = {0.f, 0.f, 0.f, 0.f};
  for (int i = 0; i < splits; ++i) {
    const float4 v = *(const float4*)(p + (size_t)i * 65536);
    s.x += v.x; s.y += v.y; s.z += v.z; s.w += v.w;
  }
  *(float4*)p = s;
}

// ----------------------------------------------------------------- kSym ----
// G = Gs + Gs^T per batch (Gs = reduced half-Gram in Gp slot 0).
// grid (16 64x64 tiles, 8 batches), 256 threads; transpose via LDS.
__global__ void kSym(const float* __restrict__ Gs, float* __restrict__ G,
                     int sstride) {
  __shared__ __align__(16) float pt[64][68];
  const int n = blockIdx.y;
  const int bi = blockIdx.x >> 2, bj = blockIdx.x & 3;
  const float* gsn = Gs + (size_t)n * sstride;
  float* gn = G + (size_t)n * 65536;
  const int t = threadIdx.x, r = t >> 2, cg = (t & 3) * 16;
#pragma unroll
  for (int e = 0; e < 16; e += 4)
    *(float4*)&pt[r][cg + e] =
        *(const float4*)(gsn + (size_t)(bj * 64 + r) * 256 + bi * 64 + cg + e);
  __syncthreads();
#pragma unroll
  for (int e = 0; e < 16; e += 4) {
    const float4 a =
        *(const float4*)(gsn + (size_t)(bi * 64 + r) * 256 + bj * 64 + cg + e);
    float4 o;
    o.x = a.x + pt[cg + e + 0][r];
    o.y = a.y + pt[cg + e + 1][r];
    o.z = a.z + pt[cg + e + 2][r];
    o.w = a.w + pt[cg + e + 3][r];
    *(float4*)(gn + (size_t)(bi * 64 + r) * 256 + bj * 64 + cg + e) = o;
  }
}

// ---------------------------------------------------------------- kAttn ----
// grid (32 row-blocks of 8, 8 batches), 256 threads (4 waves).
// P1: T = ivq*(Wq G): Wq rows via scalar pipe (uniform s_load), G via
//     lane-contiguous float4; wave w owns rows {2w, 2w+1}, lane owns 4 cols.
// P2: L = ivk*(T Wk^T) + bias: thread = col d, T rows via uniform b128.
// P3: softmax (32 lanes per row), P pre-scaled by ivv, cvec fused.
// P4: M = (P Wv)/rsum: thread = col l, P via uniform b128, Wv coalesced.
#define TLD 260   // padded fp32 LDS row stride (16B-aligned: 260*4 = 1040)
__global__ __launch_bounds__(256) void kAttn(
    const float* __restrict__ G, const float* __restrict__ rp, int splits,
    const float* __restrict__ Wq, const float* __restrict__ qga, const float* __restrict__ qbe,
    const float* __restrict__ qme, const float* __restrict__ qva,
    const float* __restrict__ Wk, const float* __restrict__ kga, const float* __restrict__ kbe,
    const float* __restrict__ kme, const float* __restrict__ kva,
    const float* __restrict__ Wv, const float* __restrict__ vga, const float* __restrict__ vbe,
    const float* __restrict__ vme, const float* __restrict__ vva,
    unsigned short* __restrict__ M, float* __restrict__ cvec) {
  __shared__ __align__(16) float t_lds[8 * TLD];
  __shared__ __align__(16) float p_lds[8 * TLD];
  __shared__ __align__(16) float r_lds[256];
  __shared__ float ivv_lds[256], bv_lds[256];
  __shared__ float rq_lds[8], bq_lds[8], rsum_lds[8];

  const int n = blockIdx.y, r0 = blockIdx.x * 8;
  const int t = threadIdx.x;
  const int lane = t & 63;
  const int w = __builtin_amdgcn_readfirstlane(t >> 6);  // force SGPR
  const float* Gn = G + (size_t)n * 65536;

  // stage r (sum of split partials), ivv, bv
  {
    float s = 0.f;
    const float* p = rp + (size_t)n * splits * 256 + t;
    for (int ss = 0; ss < splits; ++ss) s += p[ss * 256];
    r_lds[t] = s;
    const float iv = vga[t] * rsqrtf(vva[t] + EPS);
    ivv_lds[t] = iv;
    bv_lds[t] = vbe[t] - vme[t] * iv;
  }
  __syncthreads();

  // ------- P1: wave w owns rows c0 = r0+2w, c1 = c0+1; lane owns cols 4l..4l+3
  const int c0 = r0 + 2 * w, c1 = c0 + 1;
  const float ivq0 = qga[c0] * rsqrtf(qva[c0] + EPS);
  const float ivq1 = qga[c1] * rsqrtf(qva[c1] + EPS);

  // rq_i = ivq_i * (Wq_row_i . r)  (lane-parallel dot + wave reduce)
  {
    const float4 r4 = *(const float4*)(r_lds + lane * 4);
#pragma unroll
    for (int rr = 0; rr < 2; ++rr) {
      const float4 w4 = *(const float4*)(Wq + (size_t)(c0 + rr) * 256 + lane * 4);
      float s = w4.x * r4.x + w4.y * r4.y + w4.z * r4.z + w4.w * r4.w;
      s += __shfl_xor(s, 1);  s += __shfl_xor(s, 2);  s += __shfl_xor(s, 4);
      s += __shfl_xor(s, 8);  s += __shfl_xor(s, 16); s += __shfl_xor(s, 32);
      if (lane == 0) rq_lds[2 * w + rr] = s * (rr ? ivq1 : ivq0);
    }
    if (lane == 0) {
      bq_lds[2 * w + 0] = qbe[c0] - qme[c0] * ivq0;
      bq_lds[2 * w + 1] = qbe[c1] - qme[c1] * ivq1;
    }
  }

  // T rows: treg[2][4] over K=256; Wq via scalar pipe, G via float4
  {
    float4 tr0 = {0.f, 0.f, 0.f, 0.f}, tr1 = {0.f, 0.f, 0.f, 0.f};
    const float* wq0 = Wq + (size_t)c0 * 256;
    const float* wq1 = Wq + (size_t)c1 * 256;
    for (int kb = 0; kb < 256; kb += 4) {
      union { float4 v; float f[4]; } A0, A1;
      A0.v = *(const float4*)(wq0 + kb);   // uniform -> s_load_dwordx4
      A1.v = *(const float4*)(wq1 + kb);
#pragma unroll
      for (int e = 0; e < 4; ++e) {
        const float4 g4 = *(const float4*)(Gn + (size_t)(kb + e) * 256 + lane * 4);
        const float a0 = A0.f[e], a1 = A1.f[e];
        tr0.x += a0 * g4.x; tr0.y += a0 * g4.y; tr0.z += a0 * g4.z; tr0.w += a0 * g4.w;
        tr1.x += a1 * g4.x; tr1.y += a1 * g4.y; tr1.z += a1 * g4.z; tr1.w += a1 * g4.w;
      }
    }
    tr0.x *= ivq0; tr0.y *= ivq0; tr0.z *= ivq0; tr0.w *= ivq0;
    tr1.x *= ivq1; tr1.y *= ivq1; tr1.z *= ivq1; tr1.w *= ivq1;
    *(float4*)(t_lds + (2 * w + 0) * TLD + lane * 4) = tr0;
    *(float4*)(t_lds + (2 * w + 1) * TLD + lane * 4) = tr1;
  }
  __syncthreads();

  // ------- P2: thread t = column d; L[i][t] = ivk*(T_i . Wk_row) + bias
  {
    float lreg[8];
#pragma unroll
    for (int i = 0; i < 8; ++i) lreg[i] = 0.f;
    const float ivk = kga[t] * rsqrtf(kva[t] + EPS);
    const float bkd = kbe[t] - kme[t] * ivk;
    float rkd = 0.f;
    const float* wkrow = Wk + (size_t)t * 256;
    for (int jb = 0; jb < 256; jb += 4) {
      const float4 w4 = *(const float4*)(wkrow + jb);
      const float4 r4 = *(const float4*)(r_lds + jb);     // uniform b128
      rkd += w4.x * r4.x + w4.y * r4.y + w4.z * r4.z + w4.w * r4.w;
#pragma unroll
      for (int i = 0; i < 8; ++i) {
        const float4 t4 = *(const float4*)(t_lds + i * TLD + jb);  // uniform b128
        lreg[i] += t4.x * w4.x + t4.y * w4.y + t4.z * w4.z + t4.w * w4.w;
      }
    }
#pragma unroll
    for (int i = 0; i < 8; ++i)
      p_lds[i * TLD + t] = ivk * lreg[i] + rq_lds[i] * bkd +
                           bq_lds[i] * (ivk * rkd) + 16384.0f * bq_lds[i] * bkd;
  }
  __syncthreads();

  // ------- P3: softmax; row i = t>>5, 32 lanes/row, 8 cols each (d = s + u*32)
  {
    const int i = t >> 5, s = t & 31;
    float* row = p_lds + i * TLD;
    float mx = -1e30f;
#pragma unroll
    for (int u = 0; u < 8; ++u) mx = fmaxf(mx, row[s + u * 32]);
    mx = fmaxf(mx, __shfl_xor(mx, 1));
    mx = fmaxf(mx, __shfl_xor(mx, 2));
    mx = fmaxf(mx, __shfl_xor(mx, 4));
    mx = fmaxf(mx, __shfl_xor(mx, 8));
    mx = fmaxf(mx, __shfl_xor(mx, 16));
    float sraw = 0.f, sbv = 0.f;
#pragma unroll
    for (int u = 0; u < 8; ++u) {
      const int d = s + u * 32;
      const float e = __expf(row[d] - mx);
      sraw += e;
      sbv += e * bv_lds[d];
      row[d] = e * ivv_lds[d];   // pre-scale by Dv for P4
    }
    sraw += __shfl_xor(sraw, 1);  sbv += __shfl_xor(sbv, 1);
    sraw += __shfl_xor(sraw, 2);  sbv += __shfl_xor(sbv, 2);
    sraw += __shfl_xor(sraw, 4);  sbv += __shfl_xor(sbv, 4);
    sraw += __shfl_xor(sraw, 8);  sbv += __shfl_xor(sbv, 8);
    sraw += __shfl_xor(sraw, 16); sbv += __shfl_xor(sbv, 16);
    if (s == 0) {
      rsum_lds[i] = sraw;
      cvec[n * 256 + r0 + i] = sbv / sraw;
    }
  }
  __syncthreads();

  // ------- P4: M[i][t] = (P_i . Wv_col_t) / rsum_i; Wv coalesced, P uniform b128
  {
    float mreg[8];
#pragma unroll
    for (int i = 0; i < 8; ++i) mreg[i] = 0.f;
    for (int db = 0; db < 256; db += 4) {
      float wv[4];
#pragma unroll
      for (int e = 0; e < 4; ++e) wv[e] = Wv[(size_t)(db + e) * 256 + t];
#pragma unroll
      for (int i = 0; i < 8; ++i) {
        const float4 p4 = *(const float4*)(p_lds + i * TLD + db);  // uniform b128
        mreg[i] += p4.x * wv[0] + p4.y * wv[1] + p4.z * wv[2] + p4.w * wv[3];
      }
    }
#pragma unroll
    for (int i = 0; i < 8; ++i)
      M[((size_t)n * 256 + r0 + i) * 256 + t] = f2bf(mreg[i] / rsum_lds[i]);
  }
}

// ----------------------------------------------------------------- kOut ----
// grid (256 s-chunks of 64, 8 batches), 256 threads (4 waves).
// out[:,s-chunk] = M @ x_bf16 + cvec + x (fp32 residual from LDS copy).
#define LDT 40   // padded LDS row stride for transposed x tile (bf16 elems)
__global__ __launch_bounds__(256, 2) void kOut(const float* __restrict__ x,
                                               const unsigned short* __restrict__ M,
                                               const float* __restrict__ cvec,
                                               float* __restrict__ out) {
  __shared__ __align__(16) unsigned short xt[64 * LDT];  // [s][ch] bf16
  __shared__ __align__(16) float xf[256 * 64];           // [ch][s] fp32 residual
  const int n = blockIdx.y, s0 = blockIdx.x * 64;
  const int tid = threadIdx.x;
  const float* xn = x + (size_t)n * 4194304;
  const unsigned short* Mn = M + (size_t)n * 65536;
  const int lane = tid & 63, w = tid >> 6;
  const int m = lane & 15, q = lane >> 4;

  f32x4 acc[4][4];
  const f32x4 z4 = {0.f, 0.f, 0.f, 0.f};
#pragma unroll
  for (int i = 0; i < 4; ++i)
#pragma unroll
    for (int ct = 0; ct < 4; ++ct) acc[i][ct] = z4;

  for (int kt = 0; kt < 8; ++kt) {
    __syncthreads();
#pragma unroll
    for (int u = 0; u < 2; ++u) {
      const int fidx = tid + u * 256;
      const int ch = fidx >> 4, f = fidx & 15;
      const float4 v = *(const float4*)(xn + (size_t)(kt * 32 + ch) * 16384 + s0 + f * 4);
      *(float4*)&xf[(kt * 32 + ch) * 64 + f * 4] = v;
      xt[(f * 4 + 0) * LDT + ch] = f2bf(v.x);
      xt[(f * 4 + 1) * LDT + ch] = f2bf(v.y);
      xt[(f * 4 + 2) * LDT + ch] = f2bf(v.z);
      xt[(f * 4 + 3) * LDT + ch] = f2bf(v.w);
    }
    __syncthreads();
    bf16x8 A[4], B[4];
#pragma unroll
    for (int i = 0; i < 4; ++i)
      A[i] = ld_frag(&Mn[((w * 4 + i) * 16 + m) * 256 + kt * 32 + q * 8]);
#pragma unroll
    for (int ct = 0; ct < 4; ++ct)
      B[ct] = ld_frag(&xt[(ct * 16 + m) * LDT + q * 8]);
#pragma unroll
    for (int i = 0; i < 4; ++i)
#pragma unroll
      for (int ct = 0; ct < 4; ++ct)
        acc[i][ct] = __builtin_amdgcn_mfma_f32_16x16x32_bf16(A[i], B[ct], acc[i][ct], 0, 0, 0);
  }
  // epilogue: c = w*64 + i*16 + q*4 + e ; s = ct*16 + m
#pragma unroll
  for (int i = 0; i < 4; ++i) {
    const int cb = w * 64 + i * 16 + q * 4;
#pragma unroll
    for (int e = 0; e < 4; ++e) {
      const int c = cb + e;
      const float cv = cvec[n * 256 + c];
      float* orow = out + ((size_t)n * 256 + c) * 16384 + s0;
#pragma unroll
      for (int ct = 0; ct < 4; ++ct) {
        const int s = ct * 16 + m;
        orow[s] = acc[i][ct][e] + cv + xf[c * 64 + s];
      }
    }
  }
}

// --------------------------------------------------------------- launch ----
extern "C" void kernel_launch(void* const* d_in, const int* in_sizes, int n_in,
                              void* d_out, int out_size, void* d_ws, size_t ws_size,
                              hipStream_t stream) {
  const float* x   = (const float*)d_in[0];
  const float* Wk  = (const float*)d_in[1];
  const float* kga = (const float*)d_in[2];
  const float* kbe = (const float*)d_in[3];
  const float* kme = (const float*)d_in[4];
  const float* kva = (const float*)d_in[5];
  const float* Wq  = (const float*)d_in[6];
  const float* qga = (const float*)d_in[7];
  const float* qbe = (const float*)d_in[8];
  const float* qme = (const float*)d_in[9];
  const float* qva = (const float*)d_in[10];
  const float* Wv  = (const float*)d_in[11];
  const float* vga = (const float*)d_in[12];
  const float* vbe = (const float*)d_in[13];
  const float* vme = (const float*)d_in[14];
  const float* vva = (const float*)d_in[15];

  // ws layout: G (2 MB) | M (1 MB) | cvec (8 KB) | rp (256 KB) | Gp (splits*2 MB)
  // (half-Gram partial sums reduced in place into Gp slot 0; kSym -> G)
  char* ws = (char*)d_ws;
  float* G           = (float*)(ws);
  unsigned short* Mm = (unsigned short*)(ws + 2097152);
  float* cv          = (float*)(ws + 3145728);
  float* rp          = (float*)(ws + 3153920);
  float* Gp          = (float*)(ws + 3416064);
  float* out         = (float*)d_out;

  int splits = 32;
  while (splits > 1 &&
         (size_t)3416064 + (size_t)splits * 8 * 65536 * 4 > ws_size)
    splits >>= 1;
  const int chunk = 16384 / splits;

  kGram<<<dim3(splits, 8), 512, 0, stream>>>(x, Gp, rp, chunk);
  kReduce<<<512, 256, 0, stream>>>(Gp, splits);
  kSym<<<dim3(16, 8), 256, 0, stream>>>(Gp, G, splits * 65536);
  kAttn<<<dim3(32, 8), 256, 0, stream>>>(G, rp, splits,
                                         Wq, qga, qbe, qme, qva,
                                         Wk, kga, kbe, kme, kva,
                                         Wv, vga, vbe, vme, vva,
                                         Mm, cv);
  kOut<<<dim3(256, 8), 256, 0, stream>>>(x, Mm, cv, out);
}

// Round 3
// 388.128 us; speedup vs baseline: 1.0131x; 1.0131x over previous
//
#include <hip/hip_runtime.h>

// NonLocalAttention: channel attention restructured around Gram matrix.
//   G = x x^T (per batch, bf16 split precision, split-k partials + tree reduce)
//   logits = Aq G Ak^T + (Aq r) bk^T + bq (Ak r)^T + S*bq bk^T,  Aq = Dq Wq etc.
//   attn = softmax(logits, dim=-1)  (fp32)
//   M = attn Dv Wv (bf16), c = attn bv
//   out = M x + c 1^T + x   (bf16 MFMA, fp32 residual)
//
// R5 change: R3/R4 post-mortem showed kGram is stuck at ~80 us because a
// 512-thread block IS the whole CU wave budget (124 VGPR + 128 AGPR acc ->
// 2 waves/SIMD cap = 8 waves/CU = ONE block/CU). Barriers serialize stage/
// convert/MFMA with no co-resident block to overlap (m114). Fix: 256-thread
// blocks (4 waves), grid doubled via output row-halving (splits x 2 x 8),
// BK=32 single-buffer LDS (40 KB/block) -> 2 blocks/CU co-resident; phases
// of the two blocks overlap. x read twice, but sibling halves are +32 apart
// in linear WG order -> same XCD -> L2 hits. kOut: register prefetch of the
// x tile across the MFMA phase (A-frags issued before barrier so their
// vmcnt wait doesn't drain the prefetch).

typedef __bf16 bf16x8 __attribute__((ext_vector_type(8)));
typedef float f32x4 __attribute__((ext_vector_type(4)));
typedef unsigned short us8 __attribute__((ext_vector_type(8)));

#define EPS 1e-5f

__device__ __forceinline__ unsigned short f2bf(float f) {
  unsigned int u = __float_as_uint(f);
  u += 0x7fffu + ((u >> 16) & 1u);   // round-to-nearest-even
  return (unsigned short)(u >> 16);
}
__device__ __forceinline__ float bf2f(unsigned short h) {
  return __uint_as_float(((unsigned int)h) << 16);
}
__device__ __forceinline__ bf16x8 ld_frag(const unsigned short* p) {
  union { us8 u; bf16x8 b; } x;
  x.u = *(const us8*)p;
  return x.b;
}

// ---------------------------------------------------------------- kGram ----
// grid (splits, 2 halves, 8 batches), 256 threads (4 waves as 2x2 grid).
// Each WG: rows [h*128, h*128+128) x all 256 cols of P = 0.5*Xh Xh^T +
// Xh (2*Xl)^T over a `chunk`-wide S range, BK=32 tiles, single-buffer LDS,
// register-prefetched staging. Stores 0.5*acc; kSym forms G = P + P^T.
#define LDBS 40   // padded LDS row stride (bf16): 80 B, 16B-aligned

#define CONV_WRITE                                                          \
  _Pragma("unroll")                                                         \
  for (int u = 0; u < 4; ++u) {                                             \
    float fv[8] = {pa[u].x, pa[u].y, pa[u].z, pa[u].w,                      \
                   pb[u].x, pb[u].y, pb[u].z, pb[u].w};                     \
    union { unsigned short s[8]; uint4 v; } H, L;                           \
    _Pragma("unroll")                                                       \
    for (int e = 0; e < 8; ++e) {                                           \
      const unsigned short hh = f2bf(fv[e]);                                \
      H.s[e] = hh;                                                          \
      L.s[e] = f2bf(2.0f * (fv[e] - bf2f(hh)));                             \
      rs[u] += fv[e];                                                       \
    }                                                                       \
    *(uint4*)&sh[(srow + u * 64) * LDBS + sg * 8] = H.v;                    \
    *(uint4*)&sl[(srow + u * 64) * LDBS + sg * 8] = L.v;                    \
  }

__global__ __launch_bounds__(256, 2) void kGram(const float* __restrict__ x,
                                                float* __restrict__ Gp,
                                                float* __restrict__ rp,
                                                int chunk) {
  __shared__ __align__(16) unsigned short sh[256 * LDBS];  // hi
  __shared__ __align__(16) unsigned short sl[256 * LDBS];  // 2*lo
  const int n = blockIdx.z, h = blockIdx.y;
  const int k0 = blockIdx.x * chunk;
  const int nkt = chunk >> 5;                  // BK = 32
  const int tid = threadIdx.x;
  const float* xn = x + (size_t)n * 4194304;   // 256*16384

  f32x4 acc[4][8];
  const f32x4 z4 = {0.f, 0.f, 0.f, 0.f};
#pragma unroll
  for (int i = 0; i < 4; ++i)
#pragma unroll
    for (int j = 0; j < 8; ++j) acc[i][j] = z4;
  float rs[4] = {0.f, 0.f, 0.f, 0.f};

  const int lane = tid & 63, w = tid >> 6;
  const int m = lane & 15, q = lane >> 4;
  const int wr = w >> 1, wc = w & 1;          // 2x2 wave grid
  const int srow = tid >> 2, sg = tid & 3;    // staging: row 0..63 (+u*64), col group

  float4 pa[4], pb[4];

  // prologue: load tile 0 into regs
#pragma unroll
  for (int u = 0; u < 4; ++u) {
    const float* p = xn + (size_t)(srow + u * 64) * 16384 + k0 + sg * 8;
    pa[u] = *(const float4*)p;
    pb[u] = *(const float4*)(p + 4);
  }

  for (int kt = 0; kt < nkt; ++kt) {
    if (kt) __syncthreads();      // prev MFMA done reading LDS
    CONV_WRITE
    __syncthreads();
    if (kt + 1 < nkt) {           // prefetch next tile; lands during MFMA
      const int kb = k0 + (kt + 1) * 32;
#pragma unroll
      for (int u = 0; u < 4; ++u) {
        const float* p = xn + (size_t)(srow + u * 64) * 16384 + kb + sg * 8;
        pa[u] = *(const float4*)p;
        pb[u] = *(const float4*)(p + 4);
      }
    }
    // MFMA on the staged BK=32 slice (one K per 16x16x32 MFMA)
    bf16x8 Ah[4];
#pragma unroll
    for (int i = 0; i < 4; ++i)
      Ah[i] = ld_frag(&sh[(h * 128 + wr * 64 + i * 16 + m) * LDBS + q * 8]);
#pragma unroll
    for (int j = 0; j < 8; ++j) {
      const int off = (wc * 128 + j * 16 + m) * LDBS + q * 8;
      const bf16x8 Bh = ld_frag(&sh[off]);
      const bf16x8 Bl = ld_frag(&sl[off]);
#pragma unroll
      for (int i = 0; i < 4; ++i) {
        acc[i][j] = __builtin_amdgcn_mfma_f32_16x16x32_bf16(Ah[i], Bh, acc[i][j], 0, 0, 0);
        acc[i][j] = __builtin_amdgcn_mfma_f32_16x16x32_bf16(Ah[i], Bl, acc[i][j], 0, 0, 0);
      }
    }
  }

  const size_t slot = (size_t)n * gridDim.x + blockIdx.x;
  // partial row sums: each row owned by an aligned group of 4 lanes (bits 0..1)
  if (h == 0) {
#pragma unroll
    for (int u = 0; u < 4; ++u) {
      float v = rs[u];
      v += __shfl_xor(v, 1);
      v += __shfl_xor(v, 2);
      if ((lane & 3) == 0) rp[slot * 256 + (srow + u * 64)] = v;
    }
  }
  // C/D layout: col = lane&15, row = (lane>>4)*4 + reg
  float* Gpn = Gp + slot * 65536;
#pragma unroll
  for (int i = 0; i < 4; ++i)
#pragma unroll
    for (int j = 0; j < 8; ++j)
#pragma unroll
      for (int e = 0; e < 4; ++e) {
        const int grow = h * 128 + wr * 64 + i * 16 + q * 4 + e;
        const int gcol = wc * 128 + j * 16 + m;
        Gpn[grow * 256 + gcol] = 0.5f * acc[i][j][e];
      }
}

// -------------------------------------------------------------- kReduce ----
// grid 512 x 256: one thread per 4 elements (float4), sums `splits` partials
// IN PLACE into split-0's slot (read-all-then-write, per-thread exclusive).
__global__ void kReduce(float* __restrict__ Gp, int splits) {
  const int e4 = (blockIdx.x * 256 + threadIdx.x) * 4;   // 0 .. 524284
  const int n = e4 >> 16, el = e4 & 65535;
  float* p = Gp + (size_t)n * splits * 65536 + el;
  float4 s = {0.f, 0.f, 0.f, 0.f};
  for (int i = 0; i < splits; ++i) {
    const float4 v = *(const float4*)(p + (size_t)i * 65536);
    s.x += v.x; s.y += v.y; s.z += v.z; s.w += v.w;
  }
  *(float4*)p = s;
}

// ----------------------------------------------------------------- kSym ----
// G = Gs + Gs^T per batch (Gs = reduced half-Gram in Gp slot 0).
// grid (16 64x64 tiles, 8 batches), 256 threads; transpose via LDS.
__global__ void kSym(const float* __restrict__ Gs, float* __restrict__ G,
                     int sstride) {
  __shared__ __align__(16) float pt[64][68];
  const int n = blockIdx.y;
  const int bi = blockIdx.x >> 2, bj = blockIdx.x & 3;
  const float* gsn = Gs + (size_t)n * sstride;
  float* gn = G + (size_t)n * 65536;
  const int t = threadIdx.x, r = t >> 2, cg = (t & 3) * 16;
#pragma unroll
  for (int e = 0; e < 16; e += 4)
    *(float4*)&pt[r][cg + e] =
        *(const float4*)(gsn + (size_t)(bj * 64 + r) * 256 + bi * 64 + cg + e);
  __syncthreads();
#pragma unroll
  for (int e = 0; e < 16; e += 4) {
    const float4 a =
        *(const float4*)(gsn + (size_t)(bi * 64 + r) * 256 + bj * 64 + cg + e);
    float4 o;
    o.x = a.x + pt[cg + e + 0][r];
    o.y = a.y + pt[cg + e + 1][r];
    o.z = a.z + pt[cg + e + 2][r];
    o.w = a.w + pt[cg + e + 3][r];
    *(float4*)(gn + (size_t)(bi * 64 + r) * 256 + bj * 64 + cg + e) = o;
  }
}

// ---------------------------------------------------------------- kAttn ----
// grid (32 row-blocks of 8, 8 batches), 256 threads (4 waves).
// P1: T = ivq*(Wq G): Wq rows via scalar pipe (uniform s_load), G via
//     lane-contiguous float4; wave w owns rows {2w, 2w+1}, lane owns 4 cols.
// P2: L = ivk*(T Wk^T) + bias: thread = col d, T rows via uniform b128.
// P3: softmax (32 lanes per row), P pre-scaled by ivv, cvec fused.
// P4: M = (P Wv)/rsum: thread = col l, P via uniform b128, Wv coalesced.
#define TLD 260   // padded fp32 LDS row stride (16B-aligned: 260*4 = 1040)
__global__ __launch_bounds__(256) void kAttn(
    const float* __restrict__ G, const float* __restrict__ rp, int splits,
    const float* __restrict__ Wq, const float* __restrict__ qga, const float* __restrict__ qbe,
    const float* __restrict__ qme, const float* __restrict__ qva,
    const float* __restrict__ Wk, const float* __restrict__ kga, const float* __restrict__ kbe,
    const float* __restrict__ kme, const float* __restrict__ kva,
    const float* __restrict__ Wv, const float* __restrict__ vga, const float* __restrict__ vbe,
    const float* __restrict__ vme, const float* __restrict__ vva,
    unsigned short* __restrict__ M, float* __restrict__ cvec) {
  __shared__ __align__(16) float t_lds[8 * TLD];
  __shared__ __align__(16) float p_lds[8 * TLD];
  __shared__ __align__(16) float r_lds[256];
  __shared__ float ivv_lds[256], bv_lds[256];
  __shared__ float rq_lds[8], bq_lds[8], rsum_lds[8];

  const int n = blockIdx.y, r0 = blockIdx.x * 8;
  const int t = threadIdx.x;
  const int lane = t & 63;
  const int w = __builtin_amdgcn_readfirstlane(t >> 6);  // force SGPR
  const float* Gn = G + (size_t)n * 65536;

  // stage r (sum of split partials), ivv, bv
  {
    float s = 0.f;
    const float* p = rp + (size_t)n * splits * 256 + t;
    for (int ss = 0; ss < splits; ++ss) s += p[ss * 256];
    r_lds[t] = s;
    const float iv = vga[t] * rsqrtf(vva[t] + EPS);
    ivv_lds[t] = iv;
    bv_lds[t] = vbe[t] - vme[t] * iv;
  }
  __syncthreads();

  // ------- P1: wave w owns rows c0 = r0+2w, c1 = c0+1; lane owns cols 4l..4l+3
  const int c0 = r0 + 2 * w, c1 = c0 + 1;
  const float ivq0 = qga[c0] * rsqrtf(qva[c0] + EPS);
  const float ivq1 = qga[c1] * rsqrtf(qva[c1] + EPS);

  // rq_i = ivq_i * (Wq_row_i . r)  (lane-parallel dot + wave reduce)
  {
    const float4 r4 = *(const float4*)(r_lds + lane * 4);
#pragma unroll
    for (int rr = 0; rr < 2; ++rr) {
      const float4 w4 = *(const float4*)(Wq + (size_t)(c0 + rr) * 256 + lane * 4);
      float s = w4.x * r4.x + w4.y * r4.y + w4.z * r4.z + w4.w * r4.w;
      s += __shfl_xor(s, 1);  s += __shfl_xor(s, 2);  s += __shfl_xor(s, 4);
      s += __shfl_xor(s, 8);  s += __shfl_xor(s, 16); s += __shfl_xor(s, 32);
      if (lane == 0) rq_lds[2 * w + rr] = s * (rr ? ivq1 : ivq0);
    }
    if (lane == 0) {
      bq_lds[2 * w + 0] = qbe[c0] - qme[c0] * ivq0;
      bq_lds[2 * w + 1] = qbe[c1] - qme[c1] * ivq1;
    }
  }

  // T rows: treg[2][4] over K=256; Wq via scalar pipe, G via float4
  {
    float4 tr0 = {0.f, 0.f, 0.f, 0.f}, tr1 = {0.f, 0.f, 0.f, 0.f};
    const float* wq0 = Wq + (size_t)c0 * 256;
    const float* wq1 = Wq + (size_t)c1 * 256;
    for (int kb = 0; kb < 256; kb += 4) {
      union { float4 v; float f[4]; } A0, A1;
      A0.v = *(const float4*)(wq0 + kb);   // uniform -> s_load_dwordx4
      A1.v = *(const float4*)(wq1 + kb);
#pragma unroll
      for (int e = 0; e < 4; ++e) {
        const float4 g4 = *(const float4*)(Gn + (size_t)(kb + e) * 256 + lane * 4);
        const float a0 = A0.f[e], a1 = A1.f[e];
        tr0.x += a0 * g4.x; tr0.y += a0 * g4.y; tr0.z += a0 * g4.z; tr0.w += a0 * g4.w;
        tr1.x += a1 * g4.x; tr1.y += a1 * g4.y; tr1.z += a1 * g4.z; tr1.w += a1 * g4.w;
      }
    }
    tr0.x *= ivq0; tr0.y *= ivq0; tr0.z *= ivq0; tr0.w *= ivq0;
    tr1.x *= ivq1; tr1.y *= ivq1; tr1.z *= ivq1; tr1.w *= ivq1;
    *(float4*)(t_lds + (2 * w + 0) * TLD + lane * 4) = tr0;
    *(float4*)(t_lds + (2 * w + 1) * TLD + lane * 4) = tr1;
  }
  __syncthreads();

  // ------- P2: thread t = column d; L[i][t] = ivk*(T_i . Wk_row) + bias
  {
    float lreg[8];
#pragma unroll
    for (int i = 0; i < 8; ++i) lreg[i] = 0.f;
    const float ivk = kga[t] * rsqrtf(kva[t] + EPS);
    const float bkd = kbe[t] - kme[t] * ivk;
    float rkd = 0.f;
    const float* wkrow = Wk + (size_t)t * 256;
    for (int jb = 0; jb < 256; jb += 4) {
      const float4 w4 = *(const float4*)(wkrow + jb);
      const float4 r4 = *(const float4*)(r_lds + jb);     // uniform b128
      rkd += w4.x * r4.x + w4.y * r4.y + w4.z * r4.z + w4.w * r4.w;
#pragma unroll
      for (int i = 0; i < 8; ++i) {
        const float4 t4 = *(const float4*)(t_lds + i * TLD + jb);  // uniform b128
        lreg[i] += t4.x * w4.x + t4.y * w4.y + t4.z * w4.z + t4.w * w4.w;
      }
    }
#pragma unroll
    for (int i = 0; i < 8; ++i)
      p_lds[i * TLD + t] = ivk * lreg[i] + rq_lds[i] * bkd +
                           bq_lds[i] * (ivk * rkd) + 16384.0f * bq_lds[i] * bkd;
  }
  __syncthreads();

  // ------- P3: softmax; row i = t>>5, 32 lanes/row, 8 cols each (d = s + u*32)
  {
    const int i = t >> 5, s = t & 31;
    float* row = p_lds + i * TLD;
    float mx = -1e30f;
#pragma unroll
    for (int u = 0; u < 8; ++u) mx = fmaxf(mx, row[s + u * 32]);
    mx = fmaxf(mx, __shfl_xor(mx, 1));
    mx = fmaxf(mx, __shfl_xor(mx, 2));
    mx = fmaxf(mx, __shfl_xor(mx, 4));
    mx = fmaxf(mx, __shfl_xor(mx, 8));
    mx = fmaxf(mx, __shfl_xor(mx, 16));
    float sraw = 0.f, sbv = 0.f;
#pragma unroll
    for (int u = 0; u < 8; ++u) {
      const int d = s + u * 32;
      const float e = __expf(row[d] - mx);
      sraw += e;
      sbv += e * bv_lds[d];
      row[d] = e * ivv_lds[d];   // pre-scale by Dv for P4
    }
    sraw += __shfl_xor(sraw, 1);  sbv += __shfl_xor(sbv, 1);
    sraw += __shfl_xor(sraw, 2);  sbv += __shfl_xor(sbv, 2);
    sraw += __shfl_xor(sraw, 4);  sbv += __shfl_xor(sbv, 4);
    sraw += __shfl_xor(sraw, 8);  sbv += __shfl_xor(sbv, 8);
    sraw += __shfl_xor(sraw, 16); sbv += __shfl_xor(sbv, 16);
    if (s == 0) {
      rsum_lds[i] = sraw;
      cvec[n * 256 + r0 + i] = sbv / sraw;
    }
  }
  __syncthreads();

  // ------- P4: M[i][t] = (P_i . Wv_col_t) / rsum_i; Wv coalesced, P uniform b128
  {
    float mreg[8];
#pragma unroll
    for (int i = 0; i < 8; ++i) mreg[i] = 0.f;
    for (int db = 0; db < 256; db += 4) {
      float wv[4];
#pragma unroll
      for (int e = 0; e < 4; ++e) wv[e] = Wv[(size_t)(db + e) * 256 + t];
#pragma unroll
      for (int i = 0; i < 8; ++i) {
        const float4 p4 = *(const float4*)(p_lds + i * TLD + db);  // uniform b128
        mreg[i] += p4.x * wv[0] + p4.y * wv[1] + p4.z * wv[2] + p4.w * wv[3];
      }
    }
#pragma unroll
    for (int i = 0; i < 8; ++i)
      M[((size_t)n * 256 + r0 + i) * 256 + t] = f2bf(mreg[i] / rsum_lds[i]);
  }
}

// ----------------------------------------------------------------- kOut ----
// grid (256 s-chunks of 64, 8 batches), 256 threads (4 waves).
// out[:,s-chunk] = M @ x_bf16 + cvec + x (fp32 residual from LDS copy).
// R5: x tile register-prefetched across the MFMA phase; M A-frags issued
// before the barrier so their wait doesn't drain the prefetch.
#define LDT 40   // padded LDS row stride for transposed x tile (bf16 elems)
__global__ __launch_bounds__(256, 2) void kOut(const float* __restrict__ x,
                                               const unsigned short* __restrict__ M,
                                               const float* __restrict__ cvec,
                                               float* __restrict__ out) {
  __shared__ __align__(16) unsigned short xt[64 * LDT];  // [s][ch] bf16
  __shared__ __align__(16) float xf[256 * 64];           // [ch][s] fp32 residual
  const int n = blockIdx.y, s0 = blockIdx.x * 64;
  const int tid = threadIdx.x;
  const float* xn = x + (size_t)n * 4194304;
  const unsigned short* Mn = M + (size_t)n * 65536;
  const int lane = tid & 63, w = tid >> 6;
  const int m = lane & 15, q = lane >> 4;
  const int ch0 = tid >> 4, f0 = tid & 15;     // staging coords (u adds 16 ch)

  f32x4 acc[4][4];
  const f32x4 z4 = {0.f, 0.f, 0.f, 0.f};
#pragma unroll
  for (int i = 0; i < 4; ++i)
#pragma unroll
    for (int ct = 0; ct < 4; ++ct) acc[i][ct] = z4;

  float4 pv[2];
#pragma unroll
  for (int u = 0; u < 2; ++u)
    pv[u] = *(const float4*)(xn + (size_t)(ch0 + u * 16) * 16384 + s0 + f0 * 4);

  for (int kt = 0; kt < 8; ++kt) {
    if (kt) __syncthreads();           // prev MFMA done reading xt
#pragma unroll
    for (int u = 0; u < 2; ++u) {
      const int ch = kt * 32 + ch0 + u * 16;
      const float4 v = pv[u];
      *(float4*)&xf[ch * 64 + f0 * 4] = v;
      xt[(f0 * 4 + 0) * LDT + ch - kt * 32] = f2bf(v.x);
      xt[(f0 * 4 + 1) * LDT + ch - kt * 32] = f2bf(v.y);
      xt[(f0 * 4 + 2) * LDT + ch - kt * 32] = f2bf(v.z);
      xt[(f0 * 4 + 3) * LDT + ch - kt * 32] = f2bf(v.w);
    }
    // A-frags: issue BEFORE barrier (older than prefetch -> counted wait)
    bf16x8 A[4];
#pragma unroll
    for (int i = 0; i < 4; ++i)
      A[i] = ld_frag(&Mn[((w * 4 + i) * 16 + m) * 256 + kt * 32 + q * 8]);
    __syncthreads();
    if (kt < 7) {                      // prefetch next x tile during MFMA
#pragma unroll
      for (int u = 0; u < 2; ++u)
        pv[u] = *(const float4*)(xn + (size_t)((kt + 1) * 32 + ch0 + u * 16) * 16384 + s0 + f0 * 4);
    }
    bf16x8 B[4];
#pragma unroll
    for (int ct = 0; ct < 4; ++ct)
      B[ct] = ld_frag(&xt[(ct * 16 + m) * LDT + q * 8]);
#pragma unroll
    for (int i = 0; i < 4; ++i)
#pragma unroll
      for (int ct = 0; ct < 4; ++ct)
        acc[i][ct] = __builtin_amdgcn_mfma_f32_16x16x32_bf16(A[i], B[ct], acc[i][ct], 0, 0, 0);
  }
  // epilogue: c = w*64 + i*16 + q*4 + e ; s = ct*16 + m
#pragma unroll
  for (int i = 0; i < 4; ++i) {
    const int cb = w * 64 + i * 16 + q * 4;
#pragma unroll
    for (int e = 0; e < 4; ++e) {
      const int c = cb + e;
      const float cv = cvec[n * 256 + c];
      float* orow = out + ((size_t)n * 256 + c) * 16384 + s0;
#pragma unroll
      for (int ct = 0; ct < 4; ++ct) {
        const int s = ct * 16 + m;
        orow[s] = acc[i][ct][e] + cv + xf[c * 64 + s];
      }
    }
  }
}

// --------------------------------------------------------------- launch ----
extern "C" void kernel_launch(void* const* d_in, const int* in_sizes, int n_in,
                              void* d_out, int out_size, void* d_ws, size_t ws_size,
                              hipStream_t stream) {
  const float* x   = (const float*)d_in[0];
  const float* Wk  = (const float*)d_in[1];
  const float* kga = (const float*)d_in[2];
  const float* kbe = (const float*)d_in[3];
  const float* kme = (const float*)d_in[4];
  const float* kva = (const float*)d_in[5];
  const float* Wq  = (const float*)d_in[6];
  const float* qga = (const float*)d_in[7];
  const float* qbe = (const float*)d_in[8];
  const float* qme = (const float*)d_in[9];
  const float* qva = (const float*)d_in[10];
  const float* Wv  = (const float*)d_in[11];
  const float* vga = (const float*)d_in[12];
  const float* vbe = (const float*)d_in[13];
  const float* vme = (const float*)d_in[14];
  const float* vva = (const float*)d_in[15];

  // ws layout: G (2 MB) | M (1 MB) | cvec (8 KB) | rp (256 KB) | Gp (splits*2 MB)
  // (half-Gram partial sums reduced in place into Gp slot 0; kSym -> G)
  char* ws = (char*)d_ws;
  float* G           = (float*)(ws);
  unsigned short* Mm = (unsigned short*)(ws + 2097152);
  float* cv          = (float*)(ws + 3145728);
  float* rp          = (float*)(ws + 3153920);
  float* Gp          = (float*)(ws + 3416064);
  float* out         = (float*)d_out;

  int splits = 32;
  while (splits > 1 &&
         (size_t)3416064 + (size_t)splits * 8 * 65536 * 4 > ws_size)
    splits >>= 1;
  const int chunk = 16384 / splits;

  kGram<<<dim3(splits, 2, 8), 256, 0, stream>>>(x, Gp, rp, chunk);
  kReduce<<<512, 256, 0, stream>>>(Gp, splits);
  kSym<<<dim3(16, 8), 256, 0, stream>>>(Gp, G, splits * 65536);
  kAttn<<<dim3(32, 8), 256, 0, stream>>>(G, rp, splits,
                                         Wq, qga, qbe, qme, qva,
                                         Wk, kga, kbe, kme, kva,
                                         Wv, vga, vbe, vme, vva,
                                         Mm, cv);
  kOut<<<dim3(256, 8), 256, 0, stream>>>(x, Mm, cv, out);
}